// Round 1
// baseline (169.470 us; speedup 1.0000x reference)
//
#include <hip/hip_runtime.h>
#include <math.h>

#define WAVE_LDS_FENCE() asm volatile("s_waitcnt lgkmcnt(0)" ::: "memory")

constexpr int Cc = 64;
constexpr int Nn = 16384;
constexpr int Ss = 16;
constexpr int WAVES = 4;          // waves per block
constexpr int PTS_PER_WAVE = 16;  // points each wave processes

// grid = B*N / (WAVES*PTS_PER_WAVE) = 65536/64 = 1024 blocks

__global__ __launch_bounds__(256) void pt_attn_kernel(
    const float* __restrict__ xyz,      // [B,3,N]
    const float* __restrict__ nxyz,     // [B,3,N,S]
    const float* __restrict__ points,   // [B,C,N]
    const float* __restrict__ npts,     // [B,C,N,S]
    const float* __restrict__ Wk,       // [C,C]
    const float* __restrict__ Wv,       // [64,C+3]
    const float* __restrict__ Wp,       // [C,4]
    const float* __restrict__ bp,       // [C]
    float* __restrict__ out)            // [B,64,N]
{
    __shared__ float wv_lds[64 * 68];            // Wv rows padded to 68
    __shared__ float np_lds[WAVES][64 * 17];     // np tile, row stride 17 (conflict-free col reads)
    __shared__ float q_lds[WAVES][64];
    __shared__ float qk_lds[WAVES][64];
    __shared__ float attn_lds[WAVES][16];
    __shared__ float vbar_lds[WAVES][64];

    const int tid = threadIdx.x;
    const int w = tid >> 6;
    const int lane = tid & 63;
    const int s = lane & 15;
    const int g = lane >> 4;

    // ---- block-persistent weight staging ----
    for (int idx = tid; idx < 64 * 68; idx += 256) {
        int o = idx / 68;
        int c = idx - o * 68;
        wv_lds[idx] = (c < 67) ? Wv[o * 67 + c] : 0.0f;
    }

    // Wk column for this lane: wk_col[o] = Wk[o][lane]
    float wk_col[64];
#pragma unroll
    for (int o = 0; o < 64; ++o) wk_col[o] = Wk[o * 64 + lane];

    // Wp row + bias for this lane (lane acts as channel c)
    const float4 wp = ((const float4*)Wp)[lane];
    const float bpv = bp[lane];

    __syncthreads();

#pragma unroll 1
    for (int t = 0; t < PTS_PER_WAVE; ++t) {
        const int pt = blockIdx.x * (WAVES * PTS_PER_WAVE) + t * WAVES + w;
        const int b = pt >> 14;          // pt / N
        const int n = pt & (Nn - 1);     // pt % N

        // ---- per-point global loads (lane = channel c) ----
        const float4* nprow = (const float4*)(npts + ((size_t)(b * Cc + lane) * Nn + n) * Ss);
        float4 r0 = nprow[0], r1 = nprow[1], r2 = nprow[2], r3 = nprow[3];
        float qv = points[(size_t)(b * Cc + lane) * Nn + n] * 0.125f;

        // s-mapped loads (each 16-lane group redundant)
        size_t nxbase = (((size_t)(b * 3)) * Nn + n) * Ss + s;
        float d0 = xyz[(size_t)(b * 3 + 0) * Nn + n] - nxyz[nxbase];
        float d1 = xyz[(size_t)(b * 3 + 1) * Nn + n] - nxyz[nxbase + (size_t)Nn * Ss];
        float d2 = xyz[(size_t)(b * 3 + 2) * Nn + n] - nxyz[nxbase + 2 * (size_t)Nn * Ss];
        float dn = sqrtf(d0 * d0 + d1 * d1 + d2 * d2);

        // ---- stage np row + q into LDS ----
        float* myrow = &np_lds[w][lane * 17];
        myrow[0] = r0.x;  myrow[1] = r0.y;  myrow[2] = r0.z;  myrow[3] = r0.w;
        myrow[4] = r1.x;  myrow[5] = r1.y;  myrow[6] = r1.z;  myrow[7] = r1.w;
        myrow[8] = r2.x;  myrow[9] = r2.y;  myrow[10] = r2.z; myrow[11] = r2.w;
        myrow[12] = r3.x; myrow[13] = r3.y; myrow[14] = r3.z; myrow[15] = r3.w;
        q_lds[w][lane] = qv;
        WAVE_LDS_FENCE();

        // ---- qk[lane] = sum_o q[o] * Wk[o][lane]  (Wk^T q) ----
        float qk = 0.0f;
        const float4* q4 = (const float4*)q_lds[w];
#pragma unroll
        for (int o4 = 0; o4 < 16; ++o4) {
            float4 q = q4[o4];
            qk = fmaf(q.x, wk_col[4 * o4 + 0], qk);
            qk = fmaf(q.y, wk_col[4 * o4 + 1], qk);
            qk = fmaf(q.z, wk_col[4 * o4 + 2], qk);
            qk = fmaf(q.w, wk_col[4 * o4 + 3], qk);
        }
        qk_lds[w][lane] = qk;

        // ---- qkp = Wp^T qk (4 vals), qkb = qk . bp : 64-lane butterfly ----
        float p0 = qk * wp.x, p1 = qk * wp.y, p2 = qk * wp.z, p3 = qk * wp.w, p4 = qk * bpv;
#pragma unroll
        for (int m = 1; m < 64; m <<= 1) {
            p0 += __shfl_xor(p0, m);
            p1 += __shfl_xor(p1, m);
            p2 += __shfl_xor(p2, m);
            p3 += __shfl_xor(p3, m);
            p4 += __shfl_xor(p4, m);
        }

        WAVE_LDS_FENCE();

        // ---- logits: lane (g,s) sums its 16-channel slice ----
        float lp = 0.0f;
#pragma unroll
        for (int i = 0; i < 16; ++i) {
            int c = 16 * g + i;
            lp = fmaf(qk_lds[w][c], np_lds[w][c * 17 + s], lp);
        }
        lp += __shfl_xor(lp, 16);
        lp += __shfl_xor(lp, 32);
        float logit = lp + p0 * d0 + p1 * d1 + p2 * d2 + p3 * dn + p4;

        // ---- softmax over s (within 16-lane group) ----
        float mx = logit;
#pragma unroll
        for (int m = 1; m < 16; m <<= 1) mx = fmaxf(mx, __shfl_xor(mx, m));
        float e = __expf(logit - mx);
        float se = e;
#pragma unroll
        for (int m = 1; m < 16; m <<= 1) se += __shfl_xor(se, m);
        float attn = e / se;
        attn_lds[w][s] = attn;   // 4 groups write identical values — benign

        // ---- vbar tail channels (tmp): reduce over s, all lanes get sums ----
        float v0 = attn * d0, v1 = attn * d1, v2 = attn * d2;
#pragma unroll
        for (int m = 1; m < 16; m <<= 1) {
            v0 += __shfl_xor(v0, m);
            v1 += __shfl_xor(v1, m);
            v2 += __shfl_xor(v2, m);
        }

        WAVE_LDS_FENCE();

        // ---- vbar[lane] = sum_s attn[s] * np[lane][s]  (np still in regs) ----
        const float4* a4 = (const float4*)attn_lds[w];
        float4 A0 = a4[0], A1 = a4[1], A2 = a4[2], A3 = a4[3];
        float vb;
        vb  = r0.x * A0.x + r0.y * A0.y + r0.z * A0.z + r0.w * A0.w;
        vb += r1.x * A1.x + r1.y * A1.y + r1.z * A1.z + r1.w * A1.w;
        vb += r2.x * A2.x + r2.y * A2.y + r2.z * A2.z + r2.w * A2.w;
        vb += r3.x * A3.x + r3.y * A3.y + r3.z * A3.z + r3.w * A3.w;
        vbar_lds[w][lane] = vb;
        WAVE_LDS_FENCE();

        // ---- out[lane] = Wv[lane,0:64].vbar + Wv[lane,64:67].vbar3 ----
        float acc = 0.0f;
        const float4* wvrow = (const float4*)&wv_lds[lane * 68];
        const float4* vb4 = (const float4*)vbar_lds[w];
#pragma unroll
        for (int j = 0; j < 16; ++j) {
            float4 wv = wvrow[j];
            float4 vv = vb4[j];
            acc = fmaf(wv.x, vv.x, acc);
            acc = fmaf(wv.y, vv.y, acc);
            acc = fmaf(wv.z, vv.z, acc);
            acc = fmaf(wv.w, vv.w, acc);
        }
        float4 wvt = wvrow[16];
        acc += wvt.x * v0 + wvt.y * v1 + wvt.z * v2;

        out[(size_t)(b * Cc + lane) * Nn + n] = acc;
    }
}

extern "C" void kernel_launch(void* const* d_in, const int* in_sizes, int n_in,
                              void* d_out, int out_size, void* d_ws, size_t ws_size,
                              hipStream_t stream) {
    const float* xyz    = (const float*)d_in[0];
    const float* nxyz   = (const float*)d_in[1];
    const float* points = (const float*)d_in[2];
    const float* npts   = (const float*)d_in[3];
    const float* Wk     = (const float*)d_in[4];
    const float* Wv     = (const float*)d_in[5];
    const float* Wp     = (const float*)d_in[6];
    const float* bp     = (const float*)d_in[7];
    float* out = (float*)d_out;

    const int total_pts = 4 * Nn;  // B*N = 65536
    const int blocks = total_pts / (WAVES * PTS_PER_WAVE);  // 1024

    hipLaunchKernelGGL(pt_attn_kernel, dim3(blocks), dim3(256), 0, stream,
                       xyz, nxyz, points, npts, Wk, Wv, Wp, bp, out);
}

// Round 2
// 166.171 us; speedup vs baseline: 1.0198x; 1.0198x over previous
//
#include <hip/hip_runtime.h>
#include <math.h>

#define WAVE_LDS_FENCE() asm volatile("s_waitcnt lgkmcnt(0)" ::: "memory")

constexpr int Cc = 64;
constexpr int Nn = 16384;
constexpr int Ss = 16;
constexpr int WAVES = 4;          // waves per block
constexpr int PTS_PER_WAVE = 16;  // consecutive n's per wave

// ---- DPP helpers: row_ror:N = 0x120|N, pure-VALU cross-lane within rows of 16 ----
template <int CTRL>
__device__ __forceinline__ float dpp_f(float x) {
    return __int_as_float(
        __builtin_amdgcn_update_dpp(0, __float_as_int(x), CTRL, 0xF, 0xF, false));
}
// all 16 lanes of each row end with the row sum / max
__device__ __forceinline__ float rsum16(float v) {
    v += dpp_f<0x128>(v);  // ror 8
    v += dpp_f<0x124>(v);  // ror 4
    v += dpp_f<0x122>(v);  // ror 2
    v += dpp_f<0x121>(v);  // ror 1
    return v;
}
__device__ __forceinline__ float rmax16(float v) {
    v = fmaxf(v, dpp_f<0x128>(v));
    v = fmaxf(v, dpp_f<0x124>(v));
    v = fmaxf(v, dpp_f<0x122>(v));
    v = fmaxf(v, dpp_f<0x121>(v));
    return v;
}
// full 64-lane sum, result in all lanes (4 DPP + only 2 DS shuffles)
__device__ __forceinline__ float sum64(float v) {
    v = rsum16(v);
    v += __shfl_xor(v, 16);
    v += __shfl_xor(v, 32);
    return v;
}
// wave-uniform broadcast of lane l's value (VALU, no LDS)
__device__ __forceinline__ float lanebc(float v, int l) {
    return __int_as_float(__builtin_amdgcn_readlane(__float_as_int(v), l));
}

__global__ __launch_bounds__(256, 2) void pt_attn_kernel(
    const float* __restrict__ xyz,      // [B,3,N]
    const float* __restrict__ nxyz,     // [B,3,N,S]
    const float* __restrict__ points,   // [B,C,N]
    const float* __restrict__ npts,     // [B,C,N,S]
    const float* __restrict__ Wk,       // [C,C]
    const float* __restrict__ Wv,       // [64,C+3]
    const float* __restrict__ Wp,       // [C,4]
    float* __restrict__ out)            // [B,64,N]
{
    __shared__ float np_lds[WAVES][64 * 17];            // np tile, stride-17 rows
    __shared__ __align__(16) float qk_lds[WAVES][64];
    __shared__ __align__(16) float attn_lds[WAVES][16];

    const int tid = threadIdx.x;
    const int w = tid >> 6;
    const int lane = tid & 63;
    const int s = lane & 15;
    const int g = lane >> 4;

    // ---- per-lane weight registers (block-persistent) ----
    float wk[64];   // Wk column `lane`: wk[o] = Wk[o][lane]
#pragma unroll
    for (int o = 0; o < 64; ++o) wk[o] = Wk[o * 64 + lane];
    float wv[67];   // Wv row `lane`
#pragma unroll
    for (int j = 0; j < 67; ++j) wv[j] = Wv[lane * 67 + j];
    const float4 wp = ((const float4*)Wp)[lane];   // Wp row `lane`
    // bp dropped: constant-in-s logit shift cancels in softmax

    // wave handles 16 consecutive n (write-combine friendly)
    const int pt0 = blockIdx.x * (WAVES * PTS_PER_WAVE) + w * PTS_PER_WAVE;
    const int b = pt0 >> 14;
    const int n0 = pt0 & (Nn - 1);

    const float* nprow = npts + ((size_t)(b * Cc + lane) * Nn + n0) * Ss;
    const float* qrow = points + (size_t)(b * Cc + lane) * Nn + n0;
    const float* nx0p = nxyz + ((size_t)(b * 3 + 0) * Nn + n0) * Ss + s;
    const float* nx1p = nxyz + ((size_t)(b * 3 + 1) * Nn + n0) * Ss + s;
    const float* nx2p = nxyz + ((size_t)(b * 3 + 2) * Nn + n0) * Ss + s;
    const float* xp0 = xyz + (size_t)(b * 3 + 0) * Nn + n0;
    const float* xp1 = xyz + (size_t)(b * 3 + 1) * Nn + n0;
    const float* xp2 = xyz + (size_t)(b * 3 + 2) * Nn + n0;

    // ---- prologue prefetch (t = 0) ----
    const float4* np4 = (const float4*)nprow;
    float4 r0 = np4[0], r1 = np4[1], r2 = np4[2], r3 = np4[3];
    float qv = qrow[0] * 0.125f;
    float nxa = nx0p[0], nxb = nx1p[0], nxc = nx2p[0];
    float xa = xp0[0], xb = xp1[0], xc = xp2[0];

#pragma unroll 1
    for (int t = 0; t < PTS_PER_WAVE; ++t) {
        const int n = n0 + t;

        // relative position for this lane's s
        const float d0 = xa - nxa, d1 = xb - nxb, d2 = xc - nxc;
        const float dn = sqrtf(d0 * d0 + d1 * d1 + d2 * d2);

        // ---- stage np row into LDS (frees r for prefetch) ----
        {
            float* row = &np_lds[w][lane * 17];
            row[0] = r0.x;  row[1] = r0.y;  row[2] = r0.z;  row[3] = r0.w;
            row[4] = r1.x;  row[5] = r1.y;  row[6] = r1.z;  row[7] = r1.w;
            row[8] = r2.x;  row[9] = r2.y;  row[10] = r2.z; row[11] = r2.w;
            row[12] = r3.x; row[13] = r3.y; row[14] = r3.z; row[15] = r3.w;
        }

        // ---- qk[lane] = sum_o q[o] * Wk[o][lane] via readlane broadcast ----
        float b0 = 0.f, b1 = 0.f, b2 = 0.f, b3 = 0.f;
#pragma unroll
        for (int o = 0; o < 64; o += 4) {
            b0 = fmaf(lanebc(qv, o + 0), wk[o + 0], b0);
            b1 = fmaf(lanebc(qv, o + 1), wk[o + 1], b1);
            b2 = fmaf(lanebc(qv, o + 2), wk[o + 2], b2);
            b3 = fmaf(lanebc(qv, o + 3), wk[o + 3], b3);
        }
        const float qk = (b0 + b1) + (b2 + b3);
        qk_lds[w][lane] = qk;

        // ---- prefetch t+1 (r regs free; hides HBM latency under compute) ----
        float4 P0 = r0, P1 = r1, P2 = r2, P3 = r3;
        float qn = qv, nxan = nxa, nxbn = nxb, nxcn = nxc;
        float xan = xa, xbn = xb, xcn = xc;
        if (t + 1 < PTS_PER_WAVE) {
            const float4* np4n = (const float4*)(nprow + (size_t)(t + 1) * Ss);
            P0 = np4n[0]; P1 = np4n[1]; P2 = np4n[2]; P3 = np4n[3];
            qn = qrow[t + 1] * 0.125f;
            nxan = nx0p[(size_t)(t + 1) * Ss];
            nxbn = nx1p[(size_t)(t + 1) * Ss];
            nxcn = nx2p[(size_t)(t + 1) * Ss];
            xan = xp0[t + 1]; xbn = xp1[t + 1]; xcn = xp2[t + 1];
        }

        // ---- p_j = sum_c qk[c]*Wp[c][j] (64-lane reduce, mostly DPP) ----
        const float pp0 = sum64(qk * wp.x);
        const float pp1 = sum64(qk * wp.y);
        const float pp2 = sum64(qk * wp.z);
        const float pp3 = sum64(qk * wp.w);

        WAVE_LDS_FENCE();

        // ---- logits: lane (g,s) sums its 16-channel slice ----
        const float4* qk4 = (const float4*)qk_lds[w];
        float lp = 0.f;
#pragma unroll
        for (int j = 0; j < 4; ++j) {
            const float4 q4 = qk4[g * 4 + j];
            const float* col = &np_lds[w][(16 * g + 4 * j) * 17 + s];
            lp = fmaf(q4.x, col[0], lp);
            lp = fmaf(q4.y, col[17], lp);
            lp = fmaf(q4.z, col[34], lp);
            lp = fmaf(q4.w, col[51], lp);
        }
        lp += __shfl_xor(lp, 16);
        lp += __shfl_xor(lp, 32);
        const float logit = lp + pp0 * d0 + pp1 * d1 + pp2 * d2 + pp3 * dn;

        // ---- softmax over s: DPP-only within 16-lane groups ----
        const float mx = rmax16(logit);
        const float e = __expf(logit - mx);
        const float se = rsum16(e);
        const float attn = e / se;
        attn_lds[w][s] = attn;   // 4 groups write identical values — benign

        // tail channels (tmp): all lanes end with the 3 sums
        const float vt0 = rsum16(attn * d0);
        const float vt1 = rsum16(attn * d1);
        const float vt2 = rsum16(attn * d2);

        WAVE_LDS_FENCE();

        // ---- vbar[lane] = sum_s attn[s] * np[lane][s] (np from LDS) ----
        const float4* a4 = (const float4*)attn_lds[w];
        const float4 A0 = a4[0], A1 = a4[1], A2 = a4[2], A3 = a4[3];
        const float* row = &np_lds[w][lane * 17];
        float vb;
        vb  = A0.x * row[0]  + A0.y * row[1]  + A0.z * row[2]  + A0.w * row[3];
        vb += A1.x * row[4]  + A1.y * row[5]  + A1.z * row[6]  + A1.w * row[7];
        vb += A2.x * row[8]  + A2.y * row[9]  + A2.z * row[10] + A2.w * row[11];
        vb += A3.x * row[12] + A3.y * row[13] + A3.z * row[14] + A3.w * row[15];

        // ---- out[lane] = Wv[lane,:64].vbar + Wv[lane,64:67].vtail ----
        float c0 = 0.f, c1 = 0.f, c2 = 0.f, c3 = 0.f;
#pragma unroll
        for (int c = 0; c < 64; c += 4) {
            c0 = fmaf(lanebc(vb, c + 0), wv[c + 0], c0);
            c1 = fmaf(lanebc(vb, c + 1), wv[c + 1], c1);
            c2 = fmaf(lanebc(vb, c + 2), wv[c + 2], c2);
            c3 = fmaf(lanebc(vb, c + 3), wv[c + 3], c3);
        }
        float acc = (c0 + c1) + (c2 + c3);
        acc = fmaf(wv[64], vt0, acc);
        acc = fmaf(wv[65], vt1, acc);
        acc = fmaf(wv[66], vt2, acc);

        out[(size_t)(b * Cc + lane) * Nn + n] = acc;

        // rotate prefetched state
        r0 = P0; r1 = P1; r2 = P2; r3 = P3;
        qv = qn; nxa = nxan; nxb = nxbn; nxc = nxcn;
        xa = xan; xb = xbn; xc = xcn;
    }
}

extern "C" void kernel_launch(void* const* d_in, const int* in_sizes, int n_in,
                              void* d_out, int out_size, void* d_ws, size_t ws_size,
                              hipStream_t stream) {
    const float* xyz    = (const float*)d_in[0];
    const float* nxyz   = (const float*)d_in[1];
    const float* points = (const float*)d_in[2];
    const float* npts   = (const float*)d_in[3];
    const float* Wk     = (const float*)d_in[4];
    const float* Wv     = (const float*)d_in[5];
    const float* Wp     = (const float*)d_in[6];
    // d_in[7] = bp — unused: constant-in-s logit shift cancels in softmax
    float* out = (float*)d_out;

    const int total_pts = 4 * Nn;  // B*N = 65536
    const int blocks = total_pts / (WAVES * PTS_PER_WAVE);  // 1024

    hipLaunchKernelGGL(pt_attn_kernel, dim3(blocks), dim3(256), 0, stream,
                       xyz, nxyz, points, npts, Wk, Wv, Wp, out);
}